// Round 11
// baseline (244.562 us; speedup 1.0000x reference)
//
#include <hip/hip_runtime.h>

using short4_t = __attribute__((ext_vector_type(4))) short;
using short8_t = __attribute__((ext_vector_type(8))) short;
using f32x4    = __attribute__((ext_vector_type(4))) float;

#define B_SZ 2
#define T_SZ 2048
#define DM   1024
#define MROWS (B_SZ * T_SZ)   // 4096

#define BAR() asm volatile("s_barrier" ::: "memory")

__device__ __forceinline__ unsigned short f2bf(float f) {
  unsigned u = __builtin_bit_cast(unsigned, f);
  return (unsigned short)((u + 0x7FFFu + ((u >> 16) & 1u)) >> 16);
}
__device__ __forceinline__ float bf2f(unsigned short u) {
  return __builtin_bit_cast(float, (unsigned)u << 16);
}

__device__ __forceinline__ f32x4 mfma32(short8_t a, short8_t b, f32x4 c) {
  return __builtin_amdgcn_mfma_f32_16x16x32_bf16(a, b, c, 0, 0, 0);
}
__device__ __forceinline__ f32x4 mfma16(short4_t a, short4_t b, f32x4 c) {
  return __builtin_amdgcn_mfma_f32_16x16x16bf16_1k(a, b, c, 0, 0, 0);
}

__device__ __forceinline__ void gload16(const void* g, void* l) {
  __builtin_amdgcn_global_load_lds(
      (const __attribute__((address_space(1))) unsigned int*)g,
      (__attribute__((address_space(3))) unsigned int*)l, 16, 0, 0);
}

// ---------------- all weight transposes in ONE launch -----------------------
// Wq pre-scaled by C2 = (1/sqrt(64))*log2(e): QK^T MFMA output lands directly
// in the exp2 domain (validated round 8/10).
__global__ __launch_bounds__(256) void transpose_all(
    const float* __restrict__ Wq, const float* __restrict__ Wk,
    const float* __restrict__ Wv, const float* __restrict__ Wo,
    const float* __restrict__ W1, const float* __restrict__ W2,
    unsigned short* __restrict__ WqkvT, unsigned short* __restrict__ WoT,
    unsigned short* __restrict__ W1T, unsigned short* __restrict__ W2T) {
  const int bid = blockIdx.x;
  const float* in;
  unsigned short* outp;
  int K, N, tn, tk;
  if (bid < 4096) {
    const int m = bid >> 10, t = bid & 1023;
    K = 1024; N = 1024; tn = t & 31; tk = t >> 5;
    in = (m == 0) ? Wq : (m == 1) ? Wk : (m == 2) ? Wv : Wo;
    outp = (m == 3) ? WoT : (WqkvT + (size_t)m * 1024 * 1024);
  } else if (bid < 8192) {
    const int t = bid - 4096;
    K = 1024; N = 4096; tn = t & 127; tk = t >> 7;
    in = W1; outp = W1T;
  } else {
    const int t = bid - 8192;
    K = 4096; N = 1024; tn = t & 31; tk = t >> 5;
    in = W2; outp = W2T;
  }
  const float qscale = (bid < 1024) ? 0.18033688011112042f : 1.0f;
  __shared__ float tile[32][33];
  const int tx = threadIdx.x & 31, ty = threadIdx.x >> 5;
  const int n0 = tn * 32, k0 = tk * 32;
#pragma unroll
  for (int i = 0; i < 4; ++i)
    tile[ty + 8 * i][tx] = in[(size_t)(k0 + ty + 8 * i) * N + n0 + tx];
  __syncthreads();
#pragma unroll
  for (int i = 0; i < 4; ++i)
    outp[(size_t)(n0 + ty + 8 * i) * K + k0 + tx] =
        f2bf(tile[tx][ty + 8 * i] * qscale);
}

// ---------------- LayerNorm: fp32 in -> bf16 out, row = 1024 ----------------
__global__ __launch_bounds__(256) void ln_kernel(
    const float* __restrict__ X, const float* __restrict__ W,
    const float* __restrict__ Bb, unsigned short* __restrict__ Out) {
  const int row = blockIdx.x, tid = threadIdx.x;
  const float4 v = *(const float4*)(X + (size_t)row * DM + tid * 4);
  float s1 = v.x + v.y + v.z + v.w;
  float s2 = v.x * v.x + v.y * v.y + v.z * v.z + v.w * v.w;
#pragma unroll
  for (int m = 1; m < 64; m <<= 1) {
    s1 += __shfl_xor(s1, m);
    s2 += __shfl_xor(s2, m);
  }
  __shared__ float red[8];
  const int wave = tid >> 6, lane = tid & 63;
  if (lane == 0) { red[wave * 2] = s1; red[wave * 2 + 1] = s2; }
  __syncthreads();
  const float S1 = red[0] + red[2] + red[4] + red[6];
  const float S2 = red[1] + red[3] + red[5] + red[7];
  const float mu = S1 * (1.0f / DM);
  const float var = S2 * (1.0f / DM) - mu * mu;
  const float rs = rsqrtf(var + 1e-5f);
  const float4 w = *(const float4*)(W + tid * 4);
  const float4 b = *(const float4*)(Bb + tid * 4);
  ushort4 o;
  o.x = f2bf((v.x - mu) * rs * w.x + b.x);
  o.y = f2bf((v.y - mu) * rs * w.y + b.y);
  o.z = f2bf((v.z - mu) * rs * w.z + b.z);
  o.w = f2bf((v.w - mu) * rs * w.w + b.w);
  *(ushort4*)(Out + (size_t)row * DM + tid * 4) = o;
}

// ---------------- 8-phase 256x256 GEMM, BK=32, triple-buffered --------------
template <int EPI>
__global__ __launch_bounds__(512, 2) void gemm8(
    const unsigned short* __restrict__ A, const unsigned short* __restrict__ Bt,
    const float* __restrict__ Res, void* __restrict__ Out,
    unsigned short* __restrict__ P01, unsigned short* __restrict__ P23,
    int N, int K, int Ksplit) {
  __shared__ char lds[3][32768];
  const int tid = threadIdx.x;
  const int lane = tid & 63;
  const int wave = tid >> 6;
  const int lr = lane & 15, lg = lane >> 4;
  const int wm = wave >> 2, wn = wave & 3;
  const int row0 = blockIdx.y * 256, col0 = blockIdx.x * 256;
  const int k0 = blockIdx.z * Ksplit;
  const int NT = Ksplit >> 5;

  size_t aoff[2], boff[2];
#pragma unroll
  for (int j = 0; j < 2; ++j) {
    const int o = j * 8192 + tid * 16;
    const int lrow = o >> 7, w = o & 127;
    const int u = w ^ ((lrow & 7) << 4);
    const int grow = lrow + ((u >> 6) << 7);
    const int gk = (u & 63) >> 1;
    aoff[j] = (size_t)(row0 + grow) * K + k0 + gk;
    boff[j] = (size_t)(col0 + grow) * K + k0 + gk;
  }
  const int axor = ((wm << 6) | (lg << 4)) ^ ((lr & 7) << 4);
  const int bxor = (((wn >> 1) << 6) | (lg << 4)) ^ ((lr & 7) << 4);
  const int arow = lr * 128;
  const int brow = ((wn & 1) * 64 + lr) * 128;

  f32x4 acc[8][4] = {};

#pragma unroll
  for (int t = 0; t < 2; ++t) {
#pragma unroll
    for (int j = 0; j < 2; ++j)
      gload16(A + aoff[j] + t * 32, &lds[t][0] + j * 8192 + tid * 16);
#pragma unroll
    for (int j = 0; j < 2; ++j)
      gload16(Bt + boff[j] + t * 32, &lds[t][0] + 16384 + j * 8192 + tid * 16);
  }
  asm volatile("s_waitcnt vmcnt(4)" ::: "memory");
  BAR();

  int bc = 0;
  for (int t = 0; t < NT; ++t) {
    const char* Acur = &lds[bc][0];
    const char* Bcur = Acur + 16384;
    int sb = bc + 2; if (sb >= 3) sb -= 3;
    char* Stg = &lds[sb][0];
    const int tko = (t + 2 < NT) ? (t + 2) * 32 : (NT - 1) * 32;

    short8_t af[4], bf[4];
#pragma unroll
    for (int rs = 0; rs < 4; ++rs)
      af[rs] = *(const short8_t*)(Acur + arow + rs * 2048 + axor);
#pragma unroll
    for (int cs = 0; cs < 4; ++cs)
      bf[cs] = *(const short8_t*)(Bcur + brow + cs * 2048 + bxor);
#pragma unroll
    for (int j = 0; j < 2; ++j)
      gload16(A + aoff[j] + tko, Stg + j * 8192 + tid * 16);
    BAR();
    __builtin_amdgcn_s_setprio(1);
#pragma unroll
    for (int rs = 0; rs < 4; ++rs)
#pragma unroll
      for (int cs = 0; cs < 4; ++cs)
        acc[rs][cs] = mfma32(af[rs], bf[cs], acc[rs][cs]);
    __builtin_amdgcn_s_setprio(0);
    BAR();

#pragma unroll
    for (int rs = 0; rs < 4; ++rs)
      af[rs] = *(const short8_t*)(Acur + arow + (rs + 4) * 2048 + axor);
#pragma unroll
    for (int j = 0; j < 2; ++j)
      gload16(Bt + boff[j] + tko, Stg + 16384 + j * 8192 + tid * 16);
    BAR();
    __builtin_amdgcn_s_setprio(1);
#pragma unroll
    for (int rs = 0; rs < 4; ++rs)
#pragma unroll
      for (int cs = 0; cs < 4; ++cs)
        acc[rs + 4][cs] = mfma32(af[rs], bf[cs], acc[rs + 4][cs]);
    __builtin_amdgcn_s_setprio(0);
    asm volatile("s_waitcnt vmcnt(4)" ::: "memory");
    BAR();
    bc = (bc == 2) ? 0 : bc + 1;
  }
  asm volatile("s_waitcnt vmcnt(0)" ::: "memory");

#pragma unroll
  for (int rs = 0; rs < 8; ++rs)
#pragma unroll
    for (int cs = 0; cs < 4; ++cs) {
      const int gr = row0 + wm * 128 + rs * 16 + lg * 4;
      const int gc = col0 + wn * 64 + cs * 16 + lr;
#pragma unroll
      for (int r = 0; r < 4; ++r) {
        const float v = acc[rs][cs][r];
        const size_t idx = (size_t)(gr + r) * N + gc;
        if (EPI == 0) {
          ((unsigned short*)Out)[idx] = f2bf(v);
        } else if (EPI == 1) {
          ((float*)Out)[idx] = v + Res[idx];
        } else if (EPI == 2) {
          const float g = 0.5f * v * (1.0f + erff(v * 0.70710678118654752f));
          ((unsigned short*)Out)[idx] = f2bf(g);
        } else {
          unsigned short* P = (blockIdx.z >> 1) ? P23 : P01;
          P[(size_t)(blockIdx.z & 1) * MROWS * 1024 + idx] = f2bf(v);
        }
      }
    }
}

// ---------------- splitK reduce: out = X2 + sum(partials) -------------------
__global__ __launch_bounds__(256) void reduce_ffn2(
    const float* __restrict__ X2,
    const unsigned short* __restrict__ P0, const unsigned short* __restrict__ P1,
    const unsigned short* __restrict__ P2, const unsigned short* __restrict__ P3,
    int ns, float* __restrict__ Out) {
  const size_t i = ((size_t)blockIdx.x * 256 + threadIdx.x) * 4;
  float4 o = *(const float4*)(X2 + i);
  ushort4 a = *(const ushort4*)(P0 + i);
  ushort4 b = *(const ushort4*)(P1 + i);
  o.x += bf2f(a.x) + bf2f(b.x);
  o.y += bf2f(a.y) + bf2f(b.y);
  o.z += bf2f(a.z) + bf2f(b.z);
  o.w += bf2f(a.w) + bf2f(b.w);
  if (ns == 4) {
    ushort4 c = *(const ushort4*)(P2 + i);
    ushort4 d = *(const ushort4*)(P3 + i);
    o.x += bf2f(c.x) + bf2f(d.x);
    o.y += bf2f(c.y) + bf2f(d.y);
    o.z += bf2f(c.z) + bf2f(d.z);
    o.w += bf2f(c.w) + bf2f(d.w);
  }
  *(float4*)(Out + i) = o;
}

// ---------------- fused splitK-reduce + residual + LayerNorm ----------------
__global__ __launch_bounds__(256) void reduce_ln(
    const float* __restrict__ x,
    const unsigned short* __restrict__ P01, const unsigned short* __restrict__ P23,
    const float* __restrict__ W, const float* __restrict__ Bb,
    float* __restrict__ X2, unsigned short* __restrict__ H12) {
  const int row = blockIdx.x, tid = threadIdx.x;
  const size_t base = (size_t)row * DM + tid * 4;
  float4 v = *(const float4*)(x + base);
  ushort4 a = *(const ushort4*)(P01 + base);
  ushort4 b = *(const ushort4*)(P01 + (size_t)MROWS * DM + base);
  ushort4 c = *(const ushort4*)(P23 + base);
  ushort4 d = *(const ushort4*)(P23 + (size_t)MROWS * DM + base);
  v.x += bf2f(a.x) + bf2f(b.x) + bf2f(c.x) + bf2f(d.x);
  v.y += bf2f(a.y) + bf2f(b.y) + bf2f(c.y) + bf2f(d.y);
  v.z += bf2f(a.z) + bf2f(b.z) + bf2f(c.z) + bf2f(d.z);
  v.w += bf2f(a.w) + bf2f(b.w) + bf2f(c.w) + bf2f(d.w);
  *(float4*)(X2 + base) = v;
  float s1 = v.x + v.y + v.z + v.w;
  float s2 = v.x * v.x + v.y * v.y + v.z * v.z + v.w * v.w;
#pragma unroll
  for (int m = 1; m < 64; m <<= 1) {
    s1 += __shfl_xor(s1, m);
    s2 += __shfl_xor(s2, m);
  }
  __shared__ float red[8];
  const int wave = tid >> 6, lane = tid & 63;
  if (lane == 0) { red[wave * 2] = s1; red[wave * 2 + 1] = s2; }
  __syncthreads();
  const float S1 = red[0] + red[2] + red[4] + red[6];
  const float S2 = red[1] + red[3] + red[5] + red[7];
  const float mu = S1 * (1.0f / DM);
  const float var = S2 * (1.0f / DM) - mu * mu;
  const float rs = rsqrtf(var + 1e-5f);
  const float4 w = *(const float4*)(W + tid * 4);
  const float4 bb = *(const float4*)(Bb + tid * 4);
  ushort4 o;
  o.x = f2bf((v.x - mu) * rs * w.x + bb.x);
  o.y = f2bf((v.y - mu) * rs * w.y + bb.y);
  o.z = f2bf((v.z - mu) * rs * w.z + bb.z);
  o.w = f2bf((v.w - mu) * rs * w.w + bb.w);
  *(ushort4*)(H12 + base) = o;
}

// ---------------- causal flash attention (dual q-tile, distance-2 K) --------
// Round-10 tile math unchanged. Pipeline change only: K triple-buffered with
// prefetch distance 2; per-step sync = s_waitcnt vmcnt(2) + raw s_barrier so
// the next-next K tile's loads stay in flight across the barrier (T4).
__device__ __forceinline__ void attn_tile(
    const unsigned short* Kcur, const unsigned short* Vcur,
    const short8_t* qf, f32x4* acc, float& l_run, bool diag) {
  const int tid = threadIdx.x;
  const int lane = tid & 63, wave = tid >> 6;
  const int lr = lane & 15, lg = lane >> 4;
  float pv[4][4];
  float psum = 0.f;
#pragma unroll
  for (int st = 0; st < 4; ++st) {
    f32x4 s = {0.f, 0.f, 0.f, 0.f};
#pragma unroll
    for (int c = 0; c < 2; ++c) {
      const int krow = st * 16 + lr;
      short8_t kf = *(const short8_t*)((const char*)Kcur + krow * 128 +
                                       ((c * 64 + lg * 16) ^ ((krow & 7) << 4)));
      s = mfma32(kf, qf[c], s);
    }
#pragma unroll
    for (int r = 0; r < 4; ++r) {
      float sv = s[r];
      if (diag) {
        const int keyl = st * 16 + lg * 4 + r;
        sv = (keyl <= wave * 16 + lr) ? sv : -3.0e38f;
      }
      const float p = exp2f(sv);
      pv[st][r] = p;
      psum += p;
    }
  }
  psum += __shfl_xor(psum, 16);
  psum += __shfl_xor(psum, 32);
  l_run += psum;
  short4_t pa[4];
#pragma unroll
  for (int st = 0; st < 4; ++st) {
    unsigned u0, u1;
    asm("v_cvt_pk_bf16_f32 %0, %1, %2" : "=v"(u0) : "v"(pv[st][0]), "v"(pv[st][1]));
    asm("v_cvt_pk_bf16_f32 %0, %1, %2" : "=v"(u1) : "v"(pv[st][2]), "v"(pv[st][3]));
    uint2 uu;
    uu.x = u0; uu.y = u1;
    pa[st] = __builtin_bit_cast(short4_t, uu);
  }
#pragma unroll
  for (int st = 0; st < 4; ++st)
#pragma unroll
    for (int t = 0; t < 4; ++t) {
      const int row = t * 16 + lr;
      short4_t vb = *(const short4_t*)((const char*)Vcur + row * 128 +
                                       ((2 * (st * 16 + lg * 4)) ^ ((row & 7) << 4)));
      acc[t] = mfma16(pa[st], vb, acc[t]);
    }
}

__device__ __forceinline__ void attn_epilogue(
    const f32x4* acc, float l_run, int q0, int b, int h,
    unsigned short* __restrict__ out) {
  const int tid = threadIdx.x;
  const int lane = tid & 63, wave = tid >> 6;
  const int lr = lane & 15, lg = lane >> 4;
#pragma unroll
  for (int r = 0; r < 4; ++r) {
    const float lq = __shfl(l_run, lg * 4 + r);
    const float inv = 1.0f / lq;
    const int orow = q0 + wave * 16 + lg * 4 + r;
    const size_t obase = ((size_t)b * T_SZ + orow) * 1024 + h * 64 + lr;
#pragma unroll
    for (int t = 0; t < 4; ++t) out[obase + t * 16] = f2bf(acc[t][r] * inv);
  }
}

__global__ __launch_bounds__(256) void attn_kernel(
    const unsigned short* __restrict__ qkv, unsigned short* __restrict__ out) {
  __shared__ alignas(16) unsigned short Kl[3][64 * 64];
  __shared__ alignas(16) unsigned short Vt[2][64 * 64];
  const int tid = threadIdx.x;
  const int lane = tid & 63, wave = tid >> 6;
  const int lr = lane & 15, lg = lane >> 4;
  const int bid = blockIdx.x;
  const int pair = bid & 15, h = (bid >> 4) & 15, b = bid >> 8;
  const int qtA = pair, qtB = 31 - pair;
  const size_t rowbase = (size_t)b * T_SZ * 3072;
  const unsigned short* Qb = qkv + rowbase + h * 64;
  const unsigned short* Kb = qkv + rowbase + 1024 + h * 64;
  const unsigned short* Vb = qkv + rowbase + 2048 + h * 64;

  const int qrowA = qtA * 64 + wave * 16 + lr;
  const int qrowB = qtB * 64 + wave * 16 + lr;
  short8_t qfA[2], qfB[2];
#pragma unroll
  for (int c = 0; c < 2; ++c) {
    qfA[c] = *(const short8_t*)(Qb + (size_t)qrowA * 3072 + c * 32 + lg * 8);
    qfB[c] = *(const short8_t*)(Qb + (size_t)qrowB * 3072 + c * 32 + lg * 8);
  }
  f32x4 accA[4] = {}, accB[4] = {};
  float lA = 0.f, lB = 0.f;

  const int vkey = lane;
  short8_t vr[2];

  // ---- prologue: V(0) regs first, then K(0)->Kl[0], K(1)->Kl[1] ----
#pragma unroll
  for (int p = 0; p < 2; ++p) {
    const int dv0 = wave * 8 + p * 32;
    vr[p] = *(const short8_t*)(Vb + (size_t)vkey * 3072 + dv0);
  }
#pragma unroll
  for (int t = 0; t < 2; ++t)
#pragma unroll
    for (int p = 0; p < 2; ++p) {
      const int o = p * 4096 + tid * 16;
      const int key = o >> 7, c0 = o & 127;
      const int csw = c0 ^ ((key & 7) << 4);
      gload16(Kb + (size_t)(t * 64 + key) * 3072 + (csw >> 1), (char*)Kl[t] + o);
    }
#pragma unroll
  for (int p = 0; p < 2; ++p) {
    const int dv0 = wave * 8 + p * 32;
#pragma unroll
    for (int e = 0; e < 8; ++e) {
      const int row = dv0 + e;
      *(unsigned short*)((char*)Vt[0] + row * 128 + ((2 * vkey) ^ ((row & 7) << 4))) =
          (unsigned short)vr[p][e];
    }
  }
  // K(0) landed (K(1) may stay in flight); V-writes visible.
  asm volatile("s_waitcnt vmcnt(2) lgkmcnt(0)" ::: "memory");
  BAR();

  int vcur = 0, kc = 0;
  for (int i = 0; i <= qtB; ++i) {
    const int vtn = (i < qtB) ? i + 1 : qtB;       // V distance-1 (clamped)
    const int kt2 = (i + 2 <= qtB) ? i + 2 : qtB;  // K distance-2 (clamped)
    int kw = kc + 2; if (kw >= 3) kw -= 3;

    // V register loads FIRST (so their retirement leaves K gloads in flight)
#pragma unroll
    for (int p = 0; p < 2; ++p) {
      const int dv0 = wave * 8 + p * 32;
      vr[p] = *(const short8_t*)(Vb + (size_t)(vtn * 64 + vkey) * 3072 + dv0);
    }
    // K(i+2) -> Kl[kw]
#pragma unroll
    for (int p = 0; p < 2; ++p) {
      const int o = p * 4096 + tid * 16;
      const int key = o >> 7, c0 = o & 127;
      const int csw = c0 ^ ((key & 7) << 4);
      gload16(Kb + (size_t)(kt2 * 64 + key) * 3072 + (csw >> 1), (char*)Kl[kw] + o);
    }

    if (i <= qtA)
      attn_tile(Kl[kc], Vt[vcur], qfA, accA, lA, i == qtA);
    attn_tile(Kl[kc], Vt[vcur], qfB, accB, lB, i == qtB);

    // write prefetched V(i+1)
#pragma unroll
    for (int p = 0; p < 2; ++p) {
      const int dv0 = wave * 8 + p * 32;
#pragma unroll
      for (int e = 0; e < 8; ++e) {
        const int row = dv0 + e;
        *(unsigned short*)((char*)Vt[vcur ^ 1] + row * 128 +
                           ((2 * vkey) ^ ((row & 7) << 4))) = (unsigned short)vr[p][e];
      }
    }
    // K(i+1) landed; K(i+2)'s 2 loads stay in flight across the barrier.
    asm volatile("s_waitcnt vmcnt(2) lgkmcnt(0)" ::: "memory");
    BAR();
    vcur ^= 1;
    kc = (kc == 2) ? 0 : kc + 1;
  }
  attn_epilogue(accA, lA, qtA * 64, b, h, out);
  attn_epilogue(accB, lB, qtB * 64, b, h, out);
}

// ---------------- launcher ---------------------------------------------------
extern "C" void kernel_launch(void* const* d_in, const int* in_sizes, int n_in,
                              void* d_out, int out_size, void* d_ws, size_t ws_size,
                              hipStream_t stream) {
  (void)in_sizes; (void)n_in; (void)out_size;
  const float* x    = (const float*)d_in[0];
  const float* ln1w = (const float*)d_in[1];
  const float* ln1b = (const float*)d_in[2];
  const float* Wq   = (const float*)d_in[3];
  const float* Wk   = (const float*)d_in[4];
  const float* Wv   = (const float*)d_in[5];
  const float* Wo   = (const float*)d_in[6];
  const float* ln2w = (const float*)d_in[7];
  const float* ln2b = (const float*)d_in[8];
  const float* W1   = (const float*)d_in[9];
  const float* W2   = (const float*)d_in[10];
  float* out = (float*)d_out;

  char* ws = (char*)d_ws;
  unsigned short* WqkvT = (unsigned short*)(ws + 0);         // [0,6MB)
  unsigned short* WoT   = (unsigned short*)(ws + 6291456);   // [6,8MB)
  unsigned short* W1T   = (unsigned short*)(ws + 8388608);   // [8,16MB)
  unsigned short* W2T   = (unsigned short*)(ws + 16777216);  // [16,24MB)
  unsigned short* H12   = (unsigned short*)(ws + 25165824);  // [24,32MB)
  float*          X2    = (float*)(ws + 33554432);           // [32,48MB)
  unsigned short* QKV   = (unsigned short*)(ws + 50331648);  // [48,72MB)
  unsigned short* GBUF  = QKV;                               // [48,80MB) after attn
  unsigned short* WoP01 = (unsigned short*)(ws + 50331648);  // [48,64MB)
  unsigned short* WoP23 = (unsigned short*)(ws + 67108864);  // [64,80MB)
  unsigned short* P0 = (unsigned short*)(ws + 0);
  unsigned short* P1 = (unsigned short*)(ws + 8388608);
  unsigned short* P2 = (unsigned short*)(ws + 83886080);
  unsigned short* P3 = (unsigned short*)(ws + 83886080 + 8388608);
  const bool big = ws_size >= 100663296ull;

  transpose_all<<<12288, 256, 0, stream>>>(Wq, Wk, Wv, Wo, W1, W2,
                                           WqkvT, WoT, W1T, W2T);
  ln_kernel<<<MROWS, 256, 0, stream>>>(x, ln1w, ln1b, H12);
  gemm8<0><<<dim3(12, 16, 1), 512, 0, stream>>>(H12, WqkvT, nullptr, QKV,
                                                nullptr, nullptr, 3072, 1024, 1024);
  attn_kernel<<<512, 256, 0, stream>>>(QKV, H12);
  gemm8<3><<<dim3(4, 16, 4), 512, 0, stream>>>(H12, WoT, nullptr, nullptr,
                                               WoP01, WoP23, 1024, 1024, 256);
  reduce_ln<<<MROWS, 256, 0, stream>>>(x, WoP01, WoP23, ln2w, ln2b, X2, H12);
  gemm8<2><<<dim3(16, 16, 1), 512, 0, stream>>>(H12, W1T, nullptr, GBUF,
                                                nullptr, nullptr, 4096, 1024, 1024);
  if (big) {
    gemm8<3><<<dim3(4, 16, 4), 512, 0, stream>>>(GBUF, W2T, nullptr, nullptr,
                                                 P0, P2, 1024, 4096, 1024);
    reduce_ffn2<<<4096, 256, 0, stream>>>(X2, P0, P1, P2, P3, 4, out);
  } else {
    gemm8<3><<<dim3(4, 16, 2), 512, 0, stream>>>(GBUF, W2T, nullptr, nullptr,
                                                 P0, nullptr, 1024, 4096, 2048);
    reduce_ffn2<<<4096, 256, 0, stream>>>(X2, P0, P1, nullptr, nullptr, 2, out);
  }
}

// Round 12
// 236.737 us; speedup vs baseline: 1.0331x; 1.0331x over previous
//
#include <hip/hip_runtime.h>

using short4_t = __attribute__((ext_vector_type(4))) short;
using short8_t = __attribute__((ext_vector_type(8))) short;
using f32x4    = __attribute__((ext_vector_type(4))) float;

#define B_SZ 2
#define T_SZ 2048
#define DM   1024
#define MROWS (B_SZ * T_SZ)   // 4096

#define BAR() asm volatile("s_barrier" ::: "memory")

__device__ __forceinline__ unsigned short f2bf(float f) {
  unsigned u = __builtin_bit_cast(unsigned, f);
  return (unsigned short)((u + 0x7FFFu + ((u >> 16) & 1u)) >> 16);
}
__device__ __forceinline__ float bf2f(unsigned short u) {
  return __builtin_bit_cast(float, (unsigned)u << 16);
}

__device__ __forceinline__ f32x4 mfma32(short8_t a, short8_t b, f32x4 c) {
  return __builtin_amdgcn_mfma_f32_16x16x32_bf16(a, b, c, 0, 0, 0);
}
__device__ __forceinline__ f32x4 mfma16(short4_t a, short4_t b, f32x4 c) {
  return __builtin_amdgcn_mfma_f32_16x16x16bf16_1k(a, b, c, 0, 0, 0);
}

__device__ __forceinline__ void gload16(const void* g, void* l) {
  __builtin_amdgcn_global_load_lds(
      (const __attribute__((address_space(1))) unsigned int*)g,
      (__attribute__((address_space(3))) unsigned int*)l, 16, 0, 0);
}

// ---------------- fused prep: 6 weight transposes + LN1, ONE launch ---------
// bid < 12288: out[n][k] = bf16(in[k][n]) tile (Wq pre-scaled by C2).
// bid >= 12288: LN1 row (x -> H12 bf16).
__global__ __launch_bounds__(256) void prep_kernel(
    const float* __restrict__ Wq, const float* __restrict__ Wk,
    const float* __restrict__ Wv, const float* __restrict__ Wo,
    const float* __restrict__ W1, const float* __restrict__ W2,
    const float* __restrict__ x, const float* __restrict__ ln1w,
    const float* __restrict__ ln1b,
    unsigned short* __restrict__ WqkvT, unsigned short* __restrict__ WoT,
    unsigned short* __restrict__ W1T, unsigned short* __restrict__ W2T,
    unsigned short* __restrict__ H12) {
  const int bid = blockIdx.x;
  if (bid >= 12288) {
    // ---- LayerNorm row ----
    const int row = bid - 12288, tid = threadIdx.x;
    const float4 v = *(const float4*)(x + (size_t)row * DM + tid * 4);
    float s1 = v.x + v.y + v.z + v.w;
    float s2 = v.x * v.x + v.y * v.y + v.z * v.z + v.w * v.w;
#pragma unroll
    for (int m = 1; m < 64; m <<= 1) {
      s1 += __shfl_xor(s1, m);
      s2 += __shfl_xor(s2, m);
    }
    __shared__ float red[8];
    const int wave = tid >> 6, lane = tid & 63;
    if (lane == 0) { red[wave * 2] = s1; red[wave * 2 + 1] = s2; }
    __syncthreads();
    const float S1 = red[0] + red[2] + red[4] + red[6];
    const float S2 = red[1] + red[3] + red[5] + red[7];
    const float mu = S1 * (1.0f / DM);
    const float var = S2 * (1.0f / DM) - mu * mu;
    const float rs = rsqrtf(var + 1e-5f);
    const float4 w = *(const float4*)(ln1w + tid * 4);
    const float4 b = *(const float4*)(ln1b + tid * 4);
    ushort4 o;
    o.x = f2bf((v.x - mu) * rs * w.x + b.x);
    o.y = f2bf((v.y - mu) * rs * w.y + b.y);
    o.z = f2bf((v.z - mu) * rs * w.z + b.z);
    o.w = f2bf((v.w - mu) * rs * w.w + b.w);
    *(ushort4*)(H12 + (size_t)row * DM + tid * 4) = o;
    return;
  }
  // ---- weight transpose tile ----
  const float* in;
  unsigned short* outp;
  int K, N, tn, tk;
  if (bid < 4096) {
    const int m = bid >> 10, t = bid & 1023;
    K = 1024; N = 1024; tn = t & 31; tk = t >> 5;
    in = (m == 0) ? Wq : (m == 1) ? Wk : (m == 2) ? Wv : Wo;
    outp = (m == 3) ? WoT : (WqkvT + (size_t)m * 1024 * 1024);
  } else if (bid < 8192) {
    const int t = bid - 4096;
    K = 1024; N = 4096; tn = t & 127; tk = t >> 7;
    in = W1; outp = W1T;
  } else {
    const int t = bid - 8192;
    K = 4096; N = 1024; tn = t & 31; tk = t >> 5;
    in = W2; outp = W2T;
  }
  const float qscale = (bid < 1024) ? 0.18033688011112042f : 1.0f;
  __shared__ float tile[32][33];
  const int tx = threadIdx.x & 31, ty = threadIdx.x >> 5;
  const int n0 = tn * 32, k0 = tk * 32;
#pragma unroll
  for (int i = 0; i < 4; ++i)
    tile[ty + 8 * i][tx] = in[(size_t)(k0 + ty + 8 * i) * N + n0 + tx];
  __syncthreads();
#pragma unroll
  for (int i = 0; i < 4; ++i)
    outp[(size_t)(n0 + ty + 8 * i) * K + k0 + tx] =
        f2bf(tile[tx][ty + 8 * i] * qscale);
}

// ---------------- 8-phase 256x256 GEMM, BK=32, triple-buffered --------------
template <int EPI>
__global__ __launch_bounds__(512, 2) void gemm8(
    const unsigned short* __restrict__ A, const unsigned short* __restrict__ Bt,
    const float* __restrict__ Res, void* __restrict__ Out,
    unsigned short* __restrict__ P01, unsigned short* __restrict__ P23,
    int N, int K, int Ksplit) {
  __shared__ char lds[3][32768];
  const int tid = threadIdx.x;
  const int lane = tid & 63;
  const int wave = tid >> 6;
  const int lr = lane & 15, lg = lane >> 4;
  const int wm = wave >> 2, wn = wave & 3;
  const int row0 = blockIdx.y * 256, col0 = blockIdx.x * 256;
  const int k0 = blockIdx.z * Ksplit;
  const int NT = Ksplit >> 5;

  size_t aoff[2], boff[2];
#pragma unroll
  for (int j = 0; j < 2; ++j) {
    const int o = j * 8192 + tid * 16;
    const int lrow = o >> 7, w = o & 127;
    const int u = w ^ ((lrow & 7) << 4);
    const int grow = lrow + ((u >> 6) << 7);
    const int gk = (u & 63) >> 1;
    aoff[j] = (size_t)(row0 + grow) * K + k0 + gk;
    boff[j] = (size_t)(col0 + grow) * K + k0 + gk;
  }
  const int axor = ((wm << 6) | (lg << 4)) ^ ((lr & 7) << 4);
  const int bxor = (((wn >> 1) << 6) | (lg << 4)) ^ ((lr & 7) << 4);
  const int arow = lr * 128;
  const int brow = ((wn & 1) * 64 + lr) * 128;

  f32x4 acc[8][4] = {};

#pragma unroll
  for (int t = 0; t < 2; ++t) {
#pragma unroll
    for (int j = 0; j < 2; ++j)
      gload16(A + aoff[j] + t * 32, &lds[t][0] + j * 8192 + tid * 16);
#pragma unroll
    for (int j = 0; j < 2; ++j)
      gload16(Bt + boff[j] + t * 32, &lds[t][0] + 16384 + j * 8192 + tid * 16);
  }
  asm volatile("s_waitcnt vmcnt(4)" ::: "memory");
  BAR();

  int bc = 0;
  for (int t = 0; t < NT; ++t) {
    const char* Acur = &lds[bc][0];
    const char* Bcur = Acur + 16384;
    int sb = bc + 2; if (sb >= 3) sb -= 3;
    char* Stg = &lds[sb][0];
    const int tko = (t + 2 < NT) ? (t + 2) * 32 : (NT - 1) * 32;

    short8_t af[4], bf[4];
#pragma unroll
    for (int rs = 0; rs < 4; ++rs)
      af[rs] = *(const short8_t*)(Acur + arow + rs * 2048 + axor);
#pragma unroll
    for (int cs = 0; cs < 4; ++cs)
      bf[cs] = *(const short8_t*)(Bcur + brow + cs * 2048 + bxor);
#pragma unroll
    for (int j = 0; j < 2; ++j)
      gload16(A + aoff[j] + tko, Stg + j * 8192 + tid * 16);
    BAR();
    __builtin_amdgcn_s_setprio(1);
#pragma unroll
    for (int rs = 0; rs < 4; ++rs)
#pragma unroll
      for (int cs = 0; cs < 4; ++cs)
        acc[rs][cs] = mfma32(af[rs], bf[cs], acc[rs][cs]);
    __builtin_amdgcn_s_setprio(0);
    BAR();

#pragma unroll
    for (int rs = 0; rs < 4; ++rs)
      af[rs] = *(const short8_t*)(Acur + arow + (rs + 4) * 2048 + axor);
#pragma unroll
    for (int j = 0; j < 2; ++j)
      gload16(Bt + boff[j] + tko, Stg + 16384 + j * 8192 + tid * 16);
    BAR();
    __builtin_amdgcn_s_setprio(1);
#pragma unroll
    for (int rs = 0; rs < 4; ++rs)
#pragma unroll
      for (int cs = 0; cs < 4; ++cs)
        acc[rs + 4][cs] = mfma32(af[rs], bf[cs], acc[rs + 4][cs]);
    __builtin_amdgcn_s_setprio(0);
    asm volatile("s_waitcnt vmcnt(4)" ::: "memory");
    BAR();
    bc = (bc == 2) ? 0 : bc + 1;
  }
  asm volatile("s_waitcnt vmcnt(0)" ::: "memory");

#pragma unroll
  for (int rs = 0; rs < 8; ++rs)
#pragma unroll
    for (int cs = 0; cs < 4; ++cs) {
      const int gr = row0 + wm * 128 + rs * 16 + lg * 4;
      const int gc = col0 + wn * 64 + cs * 16 + lr;
#pragma unroll
      for (int r = 0; r < 4; ++r) {
        const float v = acc[rs][cs][r];
        const size_t idx = (size_t)(gr + r) * N + gc;
        if (EPI == 0) {
          ((unsigned short*)Out)[idx] = f2bf(v);
        } else if (EPI == 1) {
          ((float*)Out)[idx] = v + Res[idx];
        } else if (EPI == 2) {
          const float g = 0.5f * v * (1.0f + erff(v * 0.70710678118654752f));
          ((unsigned short*)Out)[idx] = f2bf(g);
        } else {
          unsigned short* P = (blockIdx.z >> 1) ? P23 : P01;
          P[(size_t)(blockIdx.z & 1) * MROWS * 1024 + idx] = f2bf(v);
        }
      }
    }
}

// ---------------- splitK reduce: out = X2 + sum(partials) -------------------
__global__ __launch_bounds__(256) void reduce_ffn2(
    const float* __restrict__ X2,
    const unsigned short* __restrict__ P0, const unsigned short* __restrict__ P1,
    const unsigned short* __restrict__ P2, const unsigned short* __restrict__ P3,
    int ns, float* __restrict__ Out) {
  const size_t i = ((size_t)blockIdx.x * 256 + threadIdx.x) * 4;
  float4 o = *(const float4*)(X2 + i);
  ushort4 a = *(const ushort4*)(P0 + i);
  ushort4 b = *(const ushort4*)(P1 + i);
  o.x += bf2f(a.x) + bf2f(b.x);
  o.y += bf2f(a.y) + bf2f(b.y);
  o.z += bf2f(a.z) + bf2f(b.z);
  o.w += bf2f(a.w) + bf2f(b.w);
  if (ns == 4) {
    ushort4 c = *(const ushort4*)(P2 + i);
    ushort4 d = *(const ushort4*)(P3 + i);
    o.x += bf2f(c.x) + bf2f(d.x);
    o.y += bf2f(c.y) + bf2f(d.y);
    o.z += bf2f(c.z) + bf2f(d.z);
    o.w += bf2f(c.w) + bf2f(d.w);
  }
  *(float4*)(Out + i) = o;
}

// ---------------- fused splitK-reduce + residual + LayerNorm ----------------
__global__ __launch_bounds__(256) void reduce_ln(
    const float* __restrict__ x,
    const unsigned short* __restrict__ P01, const unsigned short* __restrict__ P23,
    const float* __restrict__ W, const float* __restrict__ Bb,
    float* __restrict__ X2, unsigned short* __restrict__ H12) {
  const int row = blockIdx.x, tid = threadIdx.x;
  const size_t base = (size_t)row * DM + tid * 4;
  float4 v = *(const float4*)(x + base);
  ushort4 a = *(const ushort4*)(P01 + base);
  ushort4 b = *(const ushort4*)(P01 + (size_t)MROWS * DM + base);
  ushort4 c = *(const ushort4*)(P23 + base);
  ushort4 d = *(const ushort4*)(P23 + (size_t)MROWS * DM + base);
  v.x += bf2f(a.x) + bf2f(b.x) + bf2f(c.x) + bf2f(d.x);
  v.y += bf2f(a.y) + bf2f(b.y) + bf2f(c.y) + bf2f(d.y);
  v.z += bf2f(a.z) + bf2f(b.z) + bf2f(c.z) + bf2f(d.z);
  v.w += bf2f(a.w) + bf2f(b.w) + bf2f(c.w) + bf2f(d.w);
  *(float4*)(X2 + base) = v;
  float s1 = v.x + v.y + v.z + v.w;
  float s2 = v.x * v.x + v.y * v.y + v.z * v.z + v.w * v.w;
#pragma unroll
  for (int m = 1; m < 64; m <<= 1) {
    s1 += __shfl_xor(s1, m);
    s2 += __shfl_xor(s2, m);
  }
  __shared__ float red[8];
  const int wave = tid >> 6, lane = tid & 63;
  if (lane == 0) { red[wave * 2] = s1; red[wave * 2 + 1] = s2; }
  __syncthreads();
  const float S1 = red[0] + red[2] + red[4] + red[6];
  const float S2 = red[1] + red[3] + red[5] + red[7];
  const float mu = S1 * (1.0f / DM);
  const float var = S2 * (1.0f / DM) - mu * mu;
  const float rs = rsqrtf(var + 1e-5f);
  const float4 w = *(const float4*)(W + tid * 4);
  const float4 bb = *(const float4*)(Bb + tid * 4);
  ushort4 o;
  o.x = f2bf((v.x - mu) * rs * w.x + bb.x);
  o.y = f2bf((v.y - mu) * rs * w.y + bb.y);
  o.z = f2bf((v.z - mu) * rs * w.z + bb.z);
  o.w = f2bf((v.w - mu) * rs * w.w + bb.w);
  *(ushort4*)(H12 + base) = o;
}

// ---------------- causal flash attention (round-10 exact) -------------------
// Dual q-tile (p, 31-p) per block, 512 blocks. Scores arrive pre-scaled
// (C2 folded into Wq): mask -> exp2 -> psum shuffles.
__device__ __forceinline__ void attn_tile(
    const unsigned short* Kcur, const unsigned short* Vcur,
    const short8_t* qf, f32x4* acc, float& l_run, bool diag) {
  const int tid = threadIdx.x;
  const int lane = tid & 63, wave = tid >> 6;
  const int lr = lane & 15, lg = lane >> 4;
  float pv[4][4];
  float psum = 0.f;
#pragma unroll
  for (int st = 0; st < 4; ++st) {
    f32x4 s = {0.f, 0.f, 0.f, 0.f};
#pragma unroll
    for (int c = 0; c < 2; ++c) {
      const int krow = st * 16 + lr;
      short8_t kf = *(const short8_t*)((const char*)Kcur + krow * 128 +
                                       ((c * 64 + lg * 16) ^ ((krow & 7) << 4)));
      s = mfma32(kf, qf[c], s);
    }
#pragma unroll
    for (int r = 0; r < 4; ++r) {
      float sv = s[r];
      if (diag) {
        const int keyl = st * 16 + lg * 4 + r;
        sv = (keyl <= wave * 16 + lr) ? sv : -3.0e38f;
      }
      const float p = exp2f(sv);
      pv[st][r] = p;
      psum += p;
    }
  }
  psum += __shfl_xor(psum, 16);
  psum += __shfl_xor(psum, 32);
  l_run += psum;
  short4_t pa[4];
#pragma unroll
  for (int st = 0; st < 4; ++st) {
    unsigned u0, u1;
    asm("v_cvt_pk_bf16_f32 %0, %1, %2" : "=v"(u0) : "v"(pv[st][0]), "v"(pv[st][1]));
    asm("v_cvt_pk_bf16_f32 %0, %1, %2" : "=v"(u1) : "v"(pv[st][2]), "v"(pv[st][3]));
    uint2 uu;
    uu.x = u0; uu.y = u1;
    pa[st] = __builtin_bit_cast(short4_t, uu);
  }
#pragma unroll
  for (int st = 0; st < 4; ++st)
#pragma unroll
    for (int t = 0; t < 4; ++t) {
      const int row = t * 16 + lr;
      short4_t vb = *(const short4_t*)((const char*)Vcur + row * 128 +
                                       ((2 * (st * 16 + lg * 4)) ^ ((row & 7) << 4)));
      acc[t] = mfma16(pa[st], vb, acc[t]);
    }
}

__device__ __forceinline__ void attn_epilogue(
    const f32x4* acc, float l_run, int q0, int b, int h,
    unsigned short* __restrict__ out) {
  const int tid = threadIdx.x;
  const int lane = tid & 63, wave = tid >> 6;
  const int lr = lane & 15, lg = lane >> 4;
#pragma unroll
  for (int r = 0; r < 4; ++r) {
    const float lq = __shfl(l_run, lg * 4 + r);
    const float inv = 1.0f / lq;
    const int orow = q0 + wave * 16 + lg * 4 + r;
    const size_t obase = ((size_t)b * T_SZ + orow) * 1024 + h * 64 + lr;
#pragma unroll
    for (int t = 0; t < 4; ++t) out[obase + t * 16] = f2bf(acc[t][r] * inv);
  }
}

__global__ __launch_bounds__(256) void attn_kernel(
    const unsigned short* __restrict__ qkv, unsigned short* __restrict__ out) {
  __shared__ alignas(16) unsigned short Kl[2][64 * 64];
  __shared__ alignas(16) unsigned short Vt[2][64 * 64];
  const int tid = threadIdx.x;
  const int lane = tid & 63, wave = tid >> 6;
  const int lr = lane & 15, lg = lane >> 4;
  const int bid = blockIdx.x;
  const int pair = bid & 15, h = (bid >> 4) & 15, b = bid >> 8;
  const int qtA = pair, qtB = 31 - pair;
  const size_t rowbase = (size_t)b * T_SZ * 3072;
  const unsigned short* Qb = qkv + rowbase + h * 64;
  const unsigned short* Kb = qkv + rowbase + 1024 + h * 64;
  const unsigned short* Vb = qkv + rowbase + 2048 + h * 64;

  const int qrowA = qtA * 64 + wave * 16 + lr;
  const int qrowB = qtB * 64 + wave * 16 + lr;
  short8_t qfA[2], qfB[2];
#pragma unroll
  for (int c = 0; c < 2; ++c) {
    qfA[c] = *(const short8_t*)(Qb + (size_t)qrowA * 3072 + c * 32 + lg * 8);
    qfB[c] = *(const short8_t*)(Qb + (size_t)qrowB * 3072 + c * 32 + lg * 8);
  }
  f32x4 accA[4] = {}, accB[4] = {};
  float lA = 0.f, lB = 0.f;

  // prime tile 0
  {
#pragma unroll
    for (int p = 0; p < 2; ++p) {
      const int o = p * 4096 + tid * 16;
      const int key = o >> 7, c0 = o & 127;
      const int csw = c0 ^ ((key & 7) << 4);
      gload16(Kb + (size_t)key * 3072 + (csw >> 1), (char*)Kl[0] + o);
    }
    const int vkey = tid & 63, wv = tid >> 6;
#pragma unroll
    for (int p = 0; p < 2; ++p) {
      const int dv0 = wv * 8 + p * 32;
      short8_t v = *(const short8_t*)(Vb + (size_t)vkey * 3072 + dv0);
#pragma unroll
      for (int e = 0; e < 8; ++e) {
        const int row = dv0 + e;
        *(unsigned short*)((char*)Vt[0] + row * 128 + ((2 * vkey) ^ ((row & 7) << 4))) =
            (unsigned short)v[e];
      }
    }
    __syncthreads();
  }

  int cur = 0;
  for (int i = 0; i <= qtB; ++i) {
    const int ktn = (i < qtB) ? i + 1 : qtB;
    // issue next-tile K prefetch (direct-to-LDS) and V reg loads
#pragma unroll
    for (int p = 0; p < 2; ++p) {
      const int o = p * 4096 + tid * 16;
      const int key = o >> 7, c0 = o & 127;
      const int csw = c0 ^ ((key & 7) << 4);
      gload16(Kb + (size_t)(ktn * 64 + key) * 3072 + (csw >> 1),
              (char*)Kl[cur ^ 1] + o);
    }
    const int vkey = lane;
    short8_t vr[2];
#pragma unroll
    for (int p = 0; p < 2; ++p) {
      const int dv0 = wave * 8 + p * 32;
      vr[p] = *(const short8_t*)(Vb + (size_t)(ktn * 64 + vkey) * 3072 + dv0);
    }

    if (i <= qtA)
      attn_tile(Kl[cur], Vt[cur], qfA, accA, lA, i == qtA);
    attn_tile(Kl[cur], Vt[cur], qfB, accB, lB, i == qtB);

    // write prefetched V (regs landed during compute)
#pragma unroll
    for (int p = 0; p < 2; ++p) {
      const int dv0 = wave * 8 + p * 32;
#pragma unroll
      for (int e = 0; e < 8; ++e) {
        const int row = dv0 + e;
        *(unsigned short*)((char*)Vt[cur ^ 1] + row * 128 +
                           ((2 * vkey) ^ ((row & 7) << 4))) = (unsigned short)vr[p][e];
      }
    }
    __syncthreads();
    cur ^= 1;
  }
  attn_epilogue(accA, lA, qtA * 64, b, h, out);
  attn_epilogue(accB, lB, qtB * 64, b, h, out);
}

// ---------------- launcher ---------------------------------------------------
extern "C" void kernel_launch(void* const* d_in, const int* in_sizes, int n_in,
                              void* d_out, int out_size, void* d_ws, size_t ws_size,
                              hipStream_t stream) {
  (void)in_sizes; (void)n_in; (void)out_size;
  const float* x    = (const float*)d_in[0];
  const float* ln1w = (const float*)d_in[1];
  const float* ln1b = (const float*)d_in[2];
  const float* Wq   = (const float*)d_in[3];
  const float* Wk   = (const float*)d_in[4];
  const float* Wv   = (const float*)d_in[5];
  const float* Wo   = (const float*)d_in[6];
  const float* ln2w = (const float*)d_in[7];
  const float* ln2b = (const float*)d_in[8];
  const float* W1   = (const float*)d_in[9];
  const float* W2   = (const float*)d_in[10];
  float* out = (float*)d_out;

  char* ws = (char*)d_ws;
  unsigned short* WqkvT = (unsigned short*)(ws + 0);         // [0,6MB)
  unsigned short* WoT   = (unsigned short*)(ws + 6291456);   // [6,8MB)
  unsigned short* W1T   = (unsigned short*)(ws + 8388608);   // [8,16MB)
  unsigned short* W2T   = (unsigned short*)(ws + 16777216);  // [16,24MB)
  unsigned short* H12   = (unsigned short*)(ws + 25165824);  // [24,32MB)
  float*          X2    = (float*)(ws + 33554432);           // [32,48MB)
  unsigned short* QKV   = (unsigned short*)(ws + 50331648);  // [48,72MB)
  unsigned short* GBUF  = QKV;                               // [48,80MB) after attn
  unsigned short* WoP01 = (unsigned short*)(ws + 50331648);  // [48,64MB)
  unsigned short* WoP23 = (unsigned short*)(ws + 67108864);  // [64,80MB)
  unsigned short* P0 = (unsigned short*)(ws + 0);
  unsigned short* P1 = (unsigned short*)(ws + 8388608);
  unsigned short* P2 = (unsigned short*)(ws + 83886080);
  unsigned short* P3 = (unsigned short*)(ws + 83886080 + 8388608);
  const bool big = ws_size >= 100663296ull;

  prep_kernel<<<12288 + MROWS, 256, 0, stream>>>(
      Wq, Wk, Wv, Wo, W1, W2, x, ln1w, ln1b, WqkvT, WoT, W1T, W2T, H12);
  gemm8<0><<<dim3(12, 16, 1), 512, 0, stream>>>(H12, WqkvT, nullptr, QKV,
                                                nullptr, nullptr, 3072, 1024, 1024);
  attn_kernel<<<512, 256, 0, stream>>>(QKV, H12);
  gemm8<3><<<dim3(4, 16, 4), 512, 0, stream>>>(H12, WoT, nullptr, nullptr,
                                               WoP01, WoP23, 1024, 1024, 256);
  reduce_ln<<<MROWS, 256, 0, stream>>>(x, WoP01, WoP23, ln2w, ln2b, X2, H12);
  gemm8<2><<<dim3(16, 16, 1), 512, 0, stream>>>(H12, W1T, nullptr, GBUF,
                                                nullptr, nullptr, 4096, 1024, 1024);
  if (big) {
    gemm8<3><<<dim3(4, 16, 4), 512, 0, stream>>>(GBUF, W2T, nullptr, nullptr,
                                                 P0, P2, 1024, 4096, 1024);
    reduce_ffn2<<<4096, 256, 0, stream>>>(X2, P0, P1, P2, P3, 4, out);
  } else {
    gemm8<3><<<dim3(4, 16, 2), 512, 0, stream>>>(GBUF, W2T, nullptr, nullptr,
                                                 P0, nullptr, 1024, 4096, 2048);
    reduce_ffn2<<<4096, 256, 0, stream>>>(X2, P0, P1, nullptr, nullptr, 2, out);
  }
}